// Round 15
// baseline (28.714 us; speedup 1.0000x reference)
//
#include <hip/hip_runtime.h>
#include <math.h>

typedef __attribute__((ext_vector_type(8))) short bf16x8;
typedef __attribute__((ext_vector_type(4))) float f32x4;

namespace {
constexpr int kB   = 8192;
constexpr int kT   = 16;
constexpr int kXU  = 36;
constexpr int kCTX = 16;
constexpr int kK   = 4;
constexpr int kBT  = kB * kT;            // 131072 samples
constexpr int kMainBlocks = 512;         // 4 waves/block -> 2048 waves, 4 tiles/wave
constexpr int kNW = kMainBlocks * 4;     // 2048 wave partials per array
}

// pack two f32 -> (hi<<16)|lo bf16 pair, RNE, single instruction
__device__ __forceinline__ unsigned cvtpk(float lo, float hi) {
  unsigned r;
  asm("v_cvt_pk_bf16_f32 %0, %1, %2" : "=v"(r) : "v"(lo), "v"(hi));
  return r;
}

union Frag { bf16x8 v; unsigned u[4]; };

__device__ __forceinline__ f32x4 mfma16(bf16x8 a, bf16x8 b, f32x4 c) {
  return __builtin_amdgcn_mfma_f32_16x16x32_bf16(a, b, c, 0, 0, 0);
}

// ---------------------------------------------------------------------------
// main: transposed-GEMM MFMA pipeline, zero LDS. Round-11/13 lineage
// (26.5us, passing). ONLY change this round: TILE_LOAD(A)+TILE_LOAD(B) are
// issued BEFORE the weight-fragment prologue (pinned by sched_barrier(0)),
// so the per-wave prologue (~28 L2-hot W loads + ~80 VALU) executes under
// the first two tiles' HBM latency instead of serially ahead of it.
//
// MFMA layouts (v_mfma_f32_16x16x32_bf16):
//   A-frag: lane l holds A[row=l&15][k=8*(l>>4)+i]
//   B-frag: lane l holds B[k=8*(l>>4)+i][col=l&15]
//   D     : lane l reg i holds D[row=4*(l>>4)+i][col=l&15]
// Weight A-operand rows are permuted (pa=8*(c>>2)+(c&3), pb=pa+4) so each
// GEMM's D registers land exactly in the next GEMM's B-frag element order.
// ---------------------------------------------------------------------------

#define TILE_LOAD(S, TILEEXPR)                                                 \
  const int tile##S = (TILEEXPR);                                              \
  const int s0##S = tile##S * 16;                                              \
  float ctx_s##S = sg[tile##S * kCTX + c];                                     \
  float ctx_n##S = nz[tile##S * kCTX + c];                                     \
  float ctx_m##S = mu[tile##S * kCTX + c];                                     \
  const float* tr##S = traj + (size_t)(s0##S + c) * kXU;                       \
  float4 q0_##S = *reinterpret_cast<const float4*>(tr##S + 8 * g);             \
  float4 q1_##S = *reinterpret_cast<const float4*>(tr##S + 8 * g + 4);         \
  float4 qt_##S = *reinterpret_cast<const float4*>(tr##S + 32);                \
  float4 tc4_##S = *reinterpret_cast<const float4*>(tgtc + (size_t)(s0##S + c) * kK); \
  const float* gpb##S = tgtg + (size_t)(s0##S + c) * (kK * kXU);               \
  float4 tg0_##S[4], tg1_##S[4], tg2_##S[4];                                   \
  _Pragma("unroll")                                                            \
  for (int k = 0; k < 4; ++k) {                                                \
    tg0_##S[k] = *reinterpret_cast<const float4*>(gpb##S + k * kXU + 4 * g);   \
    tg1_##S[k] = *reinterpret_cast<const float4*>(gpb##S + k * kXU + 16 + 4 * g); \
    tg2_##S[k] = *reinterpret_cast<const float4*>(gpb##S + k * kXU + 32);      \
  }

#define TILE_COMPUTE(S)                                                        \
  {                                                                            \
    float ctxv = fmaf(ctx_s##S, ctx_n##S, ctx_m##S);                           \
    if (g == 0) {                                                              \
      ctx_out[tile##S * kCTX + c] = ctxv;                                      \
      errk += 0.5f * (ctx_s##S * ctx_s##S + ctx_m##S * ctx_m##S)               \
              - logf(ctx_s##S) - 0.5f;                                         \
    }                                                                          \
    Frag x0;                                                                   \
    x0.u[0] = cvtpk(q0_##S.x, q0_##S.y); x0.u[1] = cvtpk(q0_##S.z, q0_##S.w);  \
    x0.u[2] = cvtpk(q1_##S.x, q1_##S.y); x0.u[3] = cvtpk(q1_##S.z, q1_##S.w);  \
    float qta[4] = {qt_##S.x, qt_##S.y, qt_##S.z, qt_##S.w};                   \
    float va1[8];                                                              \
    _Pragma("unroll")                                                          \
    for (int i = 0; i < 8; ++i) {                                              \
      int k = 32 + 8 * g + i;                                                  \
      int ci = k - 36; ci = ci < 0 ? 0 : (ci > 15 ? 15 : ci);                  \
      float cv = __shfl(ctxv, ci);                                             \
      va1[i] = (k < 52) ? ((k < 36) ? qta[i & 3] : cv) : 0.f;                  \
    }                                                                          \
    Frag x1;                                                                   \
    x1.u[0] = cvtpk(va1[0], va1[1]); x1.u[1] = cvtpk(va1[2], va1[3]);          \
    x1.u[2] = cvtpk(va1[4], va1[5]); x1.u[3] = cvtpk(va1[6], va1[7]);          \
    f32x4 d1a = mfma16(w1a[0].v, x0.v, zro);                                   \
    d1a = mfma16(w1a[1].v, x1.v, d1a);                                         \
    f32x4 d1b = mfma16(w1b[0].v, x0.v, zro);                                   \
    d1b = mfma16(w1b[1].v, x1.v, d1b);                                         \
    float m1a[4], m1b[4], h1lo[4], h1hi[4];                                    \
    _Pragma("unroll")                                                          \
    for (int i = 0; i < 4; ++i) {                                              \
      float za = d1a[i] + b1l[i];                                              \
      float zb = d1b[i] + b1h[i];                                              \
      m1a[i] = (za > 0.f) ? 1.f : 0.f;                                         \
      m1b[i] = (zb > 0.f) ? 1.f : 0.f;                                         \
      h1lo[i] = fmaxf(za, 0.f);                                                \
      h1hi[i] = fmaxf(zb, 0.f);                                                \
    }                                                                          \
    Frag h1f;                                                                  \
    h1f.u[0] = cvtpk(h1lo[0], h1lo[1]); h1f.u[1] = cvtpk(h1lo[2], h1lo[3]);    \
    h1f.u[2] = cvtpk(h1hi[0], h1hi[1]); h1f.u[3] = cvtpk(h1hi[2], h1hi[3]);    \
    f32x4 d2a = mfma16(w2af.v, h1f.v, zro);                                    \
    f32x4 d2b = mfma16(w2bf.v, h1f.v, zro);                                    \
    float h2lo[4], h2hi[4];                                                    \
    unsigned m2lo[4], m2hi[4];                                                 \
    _Pragma("unroll")                                                          \
    for (int i = 0; i < 4; ++i) {                                              \
      float za = d2a[i] + b2l[i];                                              \
      float zb = d2b[i] + b2h[i];                                              \
      m2lo[i] = (za > 0.f) ? 0x3F80u : 0u;                                     \
      m2hi[i] = (zb > 0.f) ? 0x3F80u : 0u;                                     \
      h2lo[i] = fmaxf(za, 0.f);                                                \
      h2hi[i] = fmaxf(zb, 0.f);                                                \
    }                                                                          \
    Frag h2f;                                                                  \
    h2f.u[0] = cvtpk(h2lo[0], h2lo[1]); h2f.u[1] = cvtpk(h2lo[2], h2lo[3]);    \
    h2f.u[2] = cvtpk(h2hi[0], h2hi[1]); h2f.u[3] = cvtpk(h2hi[2], h2hi[3]);    \
    Frag m2f;                                                                  \
    m2f.u[0] = m2lo[0] | (m2lo[1] << 16); m2f.u[1] = m2lo[2] | (m2lo[3] << 16);\
    m2f.u[2] = m2hi[0] | (m2hi[1] << 16); m2f.u[3] = m2hi[2] | (m2hi[3] << 16);\
    f32x4 pacc = mfma16(w3f.v, h2f.v, zro);                                    \
    if (g == 0) {                                                              \
      float tv[4] = {tc4_##S.x, tc4_##S.y, tc4_##S.z, tc4_##S.w};              \
      _Pragma("unroll")                                                        \
      for (int i = 0; i < 4; ++i) {                                            \
        float d = (pacc[i] + b3a[i]) - tv[i];                                  \
        errc = fmaf(d, d, errc);                                               \
      }                                                                        \
    }                                                                          \
    _Pragma("unroll")                                                          \
    for (int k = 0; k < 4; ++k) {                                              \
      f32x4 ca = mfma16(uka[k].v, m2f.v, zro);                                 \
      f32x4 cb = mfma16(ukb[k].v, m2f.v, zro);                                 \
      float ta[4], tb[4];                                                      \
      _Pragma("unroll")                                                        \
      for (int i = 0; i < 4; ++i) {                                            \
        ta[i] = ca[i] * m1a[i];                                                \
        tb[i] = cb[i] * m1b[i];                                                \
      }                                                                        \
      Frag tf;                                                                 \
      tf.u[0] = cvtpk(ta[0], ta[1]); tf.u[1] = cvtpk(ta[2], ta[3]);            \
      tf.u[2] = cvtpk(tb[0], tb[1]); tf.u[3] = cvtpk(tb[2], tb[3]);            \
      _Pragma("unroll")                                                        \
      for (int jj = 0; jj < 3; ++jj) {                                         \
        f32x4 j4 = mfma16(w1vf[jj].v, tf.v, zro);                              \
        if (jj == 0) {                                                         \
          float tv[4] = {tg0_##S[k].x, tg0_##S[k].y, tg0_##S[k].z, tg0_##S[k].w}; \
          _Pragma("unroll")                                                    \
          for (int i = 0; i < 4; ++i) {                                        \
            float d = j4[i] - tv[i];                                           \
            errg = fmaf(d, d, errg);                                           \
          }                                                                    \
        } else if (jj == 1) {                                                  \
          float tv[4] = {tg1_##S[k].x, tg1_##S[k].y, tg1_##S[k].z, tg1_##S[k].w}; \
          _Pragma("unroll")                                                    \
          for (int i = 0; i < 4; ++i) {                                        \
            float d = j4[i] - tv[i];                                           \
            errg = fmaf(d, d, errg);                                           \
          }                                                                    \
        } else if (g == 0) {                                                   \
          float tv[4] = {tg2_##S[k].x, tg2_##S[k].y, tg2_##S[k].z, tg2_##S[k].w}; \
          _Pragma("unroll")                                                    \
          for (int i = 0; i < 4; ++i) {                                        \
            float d = j4[i] - tv[i];                                           \
            errg = fmaf(d, d, errg);                                           \
          }                                                                    \
        }                                                                      \
      }                                                                        \
    }                                                                          \
  }

__global__ __launch_bounds__(256, 2) void main_mfma(
    const float* __restrict__ traj, const float* __restrict__ tgtc,
    const float* __restrict__ tgtg, const float* __restrict__ mu,
    const float* __restrict__ sg, const float* __restrict__ nz,
    const float* __restrict__ W1, const float* __restrict__ b1,
    const float* __restrict__ W2, const float* __restrict__ b2,
    const float* __restrict__ W3, const float* __restrict__ b3,
    float* __restrict__ ctx_out,
    float* __restrict__ pc, float* __restrict__ pg, float* __restrict__ pk)
{
  const int tid = threadIdx.x;
  const int l = tid & 63;
  const int g = l >> 4;       // k-chunk group
  const int c = l & 15;       // sample column / A-row
  const int wid = blockIdx.x * 4 + (tid >> 6);
  const int pa = 8 * (c >> 2) + (c & 3);   // permuted feature for A rows (1st half)
  const int pb = pa + 4;                   // 2nd half

  const f32x4 zro = {0.f, 0.f, 0.f, 0.f};

  float errc = 0.f, errg = 0.f, errk = 0.f;

  // ============ tiles A,B loads FIRST: stream in flight during prologue ====
  TILE_LOAD(A, wid * 4)
  TILE_LOAD(B, wid * 4 + 1)
  __builtin_amdgcn_sched_barrier(0);

  // ===================== prologue: weight fragments =====================
  Frag w1a[2], w1b[2];
#pragma unroll
  for (int kt = 0; kt < 2; ++kt) {
    float va[8], vb[8];
#pragma unroll
    for (int i = 0; i < 8; ++i) {
      int kk = kt * 32 + 8 * g + i;
      va[i] = (kk < 52) ? W1[kk * 32 + pa] : 0.f;
      vb[i] = (kk < 52) ? W1[kk * 32 + pb] : 0.f;
    }
#pragma unroll
    for (int q = 0; q < 4; ++q) {
      w1a[kt].u[q] = cvtpk(va[2 * q], va[2 * q + 1]);
      w1b[kt].u[q] = cvtpk(vb[2 * q], vb[2 * q + 1]);
    }
  }

  Frag w2af, w2bf;
  {
    float va[8], vb[8];
#pragma unroll
    for (int i = 0; i < 8; ++i) {
      va[i] = W2[(8 * g + i) * 32 + pa];
      vb[i] = W2[(8 * g + i) * 32 + pb];
    }
#pragma unroll
    for (int q = 0; q < 4; ++q) {
      w2af.u[q] = cvtpk(va[2 * q], va[2 * q + 1]);
      w2bf.u[q] = cvtpk(vb[2 * q], vb[2 * q + 1]);
    }
  }

  Frag w3f;
  {
    float va[8];
#pragma unroll
    for (int i = 0; i < 8; ++i)
      va[i] = (c < 4) ? W3[(8 * g + i) * 4 + c] : 0.f;
#pragma unroll
    for (int q = 0; q < 4; ++q) w3f.u[q] = cvtpk(va[2 * q], va[2 * q + 1]);
  }

  // U_k^T A-frags: U_k^T[j][h] = W3[h][k]*W2[j][h], rows j permuted.
  float w3v[8][4];
#pragma unroll
  for (int i = 0; i < 8; ++i) {
    float4 q = *reinterpret_cast<const float4*>(W3 + (8 * g + i) * 4);
    w3v[i][0] = q.x; w3v[i][1] = q.y; w3v[i][2] = q.z; w3v[i][3] = q.w;
  }
  float w2ra[8], w2rb[8];
  {
    float4 a0 = *reinterpret_cast<const float4*>(W2 + pa * 32 + 8 * g);
    float4 a1 = *reinterpret_cast<const float4*>(W2 + pa * 32 + 8 * g + 4);
    float4 b0 = *reinterpret_cast<const float4*>(W2 + pb * 32 + 8 * g);
    float4 b1q = *reinterpret_cast<const float4*>(W2 + pb * 32 + 8 * g + 4);
    w2ra[0]=a0.x; w2ra[1]=a0.y; w2ra[2]=a0.z; w2ra[3]=a0.w;
    w2ra[4]=a1.x; w2ra[5]=a1.y; w2ra[6]=a1.z; w2ra[7]=a1.w;
    w2rb[0]=b0.x; w2rb[1]=b0.y; w2rb[2]=b0.z; w2rb[3]=b0.w;
    w2rb[4]=b1q.x; w2rb[5]=b1q.y; w2rb[6]=b1q.z; w2rb[7]=b1q.w;
  }
  Frag uka[4], ukb[4];
#pragma unroll
  for (int k = 0; k < 4; ++k) {
#pragma unroll
    for (int q = 0; q < 4; ++q) {
      uka[k].u[q] = cvtpk(w3v[2*q][k] * w2ra[2*q], w3v[2*q+1][k] * w2ra[2*q+1]);
      ukb[k].u[q] = cvtpk(w3v[2*q][k] * w2rb[2*q], w3v[2*q+1][k] * w2rb[2*q+1]);
    }
  }

  // J A-frags: rows x natural (output stays in D layout for float4 target cmp)
  Frag w1vf[3];
#pragma unroll
  for (int jj = 0; jj < 3; ++jj) {
    int x = 16 * jj + c;
    float va[8] = {0,0,0,0,0,0,0,0};
    if (x < kXU) {
      float4 p0 = *reinterpret_cast<const float4*>(W1 + x * 32 + 8 * g);
      float4 p1 = *reinterpret_cast<const float4*>(W1 + x * 32 + 8 * g + 4);
      va[0]=p0.x; va[1]=p0.y; va[2]=p0.z; va[3]=p0.w;
      va[4]=p1.x; va[5]=p1.y; va[6]=p1.z; va[7]=p1.w;
    }
#pragma unroll
    for (int q = 0; q < 4; ++q) w1vf[jj].u[q] = cvtpk(va[2*q], va[2*q+1]);
  }

  // biases (per-lane feature sets)
  float b1l[4], b1h[4], b2l[4], b2h[4], b3a[4];
  {
    float4 t0 = *reinterpret_cast<const float4*>(b1 + 8 * g);
    float4 t1 = *reinterpret_cast<const float4*>(b1 + 8 * g + 4);
    b1l[0]=t0.x; b1l[1]=t0.y; b1l[2]=t0.z; b1l[3]=t0.w;
    b1h[0]=t1.x; b1h[1]=t1.y; b1h[2]=t1.z; b1h[3]=t1.w;
    float4 r0 = *reinterpret_cast<const float4*>(b2 + 8 * g);
    float4 r1 = *reinterpret_cast<const float4*>(b2 + 8 * g + 4);
    b2l[0]=r0.x; b2l[1]=r0.y; b2l[2]=r0.z; b2l[3]=r0.w;
    b2h[0]=r1.x; b2h[1]=r1.y; b2h[2]=r1.z; b2h[3]=r1.w;
    float4 s0q = *reinterpret_cast<const float4*>(b3);
    b3a[0]=s0q.x; b3a[1]=s0q.y; b3a[2]=s0q.z; b3a[3]=s0q.w;
  }

  // ===================== 4-tile software pipeline =====================
  TILE_COMPUTE(A)
  TILE_LOAD(C, wid * 4 + 2)
  __builtin_amdgcn_sched_barrier(0);
  TILE_COMPUTE(B)
  TILE_LOAD(D, wid * 4 + 3)
  __builtin_amdgcn_sched_barrier(0);
  TILE_COMPUTE(C)
  TILE_COMPUTE(D)

  // ---- wave reduction (deterministic), one partial triple per wave ----
#pragma unroll
  for (int off = 32; off > 0; off >>= 1) {
    errc += __shfl_down(errc, off);
    errg += __shfl_down(errg, off);
    errk += __shfl_down(errk, off);
  }
  if (l == 0) { pc[wid] = errc; pg[wid] = errg; pk[wid] = errk; }
}

// ---------------------------------------------------------------------------
// finalize: reduce 2048 pc + 2048 pg + 2048 pk partials, write loss
// ---------------------------------------------------------------------------
__global__ __launch_bounds__(256) void finalize_kernel(
    const float* __restrict__ ws, float* __restrict__ out)
{
  const int tid = threadIdx.x;
  float cs = 0.f, gs = 0.f, ks = 0.f;
#pragma unroll
  for (int i = 0; i < 8; ++i) {
    cs += ws[tid + i * 256];
    gs += ws[kNW + tid + i * 256];
    ks += ws[2 * kNW + tid + i * 256];
  }
  __shared__ float rc[256], rg[256], rk[256];
  rc[tid] = cs; rg[tid] = gs; rk[tid] = ks;
  __syncthreads();
  for (int off = 128; off > 0; off >>= 1) {
    if (tid < off) {
      rc[tid] += rc[tid + off];
      rg[tid] += rg[tid + off];
      rk[tid] += rk[tid + off];
    }
    __syncthreads();
  }
  if (tid == 0) {
    out[0] = rc[0] / (float)(kBT * kK)
           + rg[0] / ((float)kBT * (float)(kK * kXU))
           + rk[0] / (float)(kB * kCTX);
  }
}

// ---------------------------------------------------------------------------
extern "C" void kernel_launch(void* const* d_in, const int* in_sizes, int n_in,
                              void* d_out, int out_size, void* d_ws, size_t ws_size,
                              hipStream_t stream)
{
  const float* traj = (const float*)d_in[0];
  const float* tgtc = (const float*)d_in[1];
  const float* tgtg = (const float*)d_in[2];
  const float* mu   = (const float*)d_in[3];
  const float* sg   = (const float*)d_in[4];
  const float* nz   = (const float*)d_in[5];
  const float* W1   = (const float*)d_in[6];
  const float* b1   = (const float*)d_in[7];
  const float* W2   = (const float*)d_in[8];
  const float* b2   = (const float*)d_in[9];
  const float* W3   = (const float*)d_in[10];
  const float* b3   = (const float*)d_in[11];

  float* out = (float*)d_out;
  float* ws  = (float*)d_ws;
  float* pc  = ws;                 // [0, 2048)
  float* pg  = ws + kNW;           // [2048, 4096)
  float* pk  = ws + 2 * kNW;       // [4096, 6144)

  main_mfma<<<kMainBlocks, 256, 0, stream>>>(traj, tgtc, tgtg, mu, sg, nz,
                                             W1, b1, W2, b2, W3, b3,
                                             out + 1, pc, pg, pk);
  finalize_kernel<<<1, 256, 0, stream>>>(ws, out);
}

// Round 16
// 26.417 us; speedup vs baseline: 1.0869x; 1.0869x over previous
//
#include <hip/hip_runtime.h>
#include <math.h>

typedef __attribute__((ext_vector_type(8))) short bf16x8;
typedef __attribute__((ext_vector_type(4))) float f32x4;

namespace {
constexpr int kB   = 8192;
constexpr int kT   = 16;
constexpr int kXU  = 36;
constexpr int kCTX = 16;
constexpr int kK   = 4;
constexpr int kBT  = kB * kT;            // 131072 samples
constexpr int kMainBlocks = 512;         // 4 waves/block -> 2048 waves, 4 tiles/wave
constexpr int kNW = kMainBlocks * 4;     // 2048 wave partials per array
}

// pack two f32 -> (hi<<16)|lo bf16 pair, RNE, single instruction
__device__ __forceinline__ unsigned cvtpk(float lo, float hi) {
  unsigned r;
  asm("v_cvt_pk_bf16_f32 %0, %1, %2" : "=v"(r) : "v"(lo), "v"(hi));
  return r;
}

union Frag { bf16x8 v; unsigned u[4]; };

__device__ __forceinline__ f32x4 mfma16(bf16x8 a, bf16x8 b, f32x4 c) {
  return __builtin_amdgcn_mfma_f32_16x16x32_bf16(a, b, c, 0, 0, 0);
}

// ---------------------------------------------------------------------------
// main: transposed-GEMM MFMA pipeline, zero LDS. EXACT revert to the
// round-11/13 kernel (26.5us, passing, twice reproduced): ctx/KL fused in,
// 4 tiles/wave software pipeline LA LB | CA, LC | CB, LD | CC, CD with
// sched_barrier(0) after each load group, prologue FIRST (r14's load-first
// variant regressed to 28.7us), separate finalize kernel (r12's fused
// finalize regressed to 43.9us).
//
// MFMA layouts (v_mfma_f32_16x16x32_bf16):
//   A-frag: lane l holds A[row=l&15][k=8*(l>>4)+i]
//   B-frag: lane l holds B[k=8*(l>>4)+i][col=l&15]
//   D     : lane l reg i holds D[row=4*(l>>4)+i][col=l&15]
// Weight A-operand rows are permuted (pa=8*(c>>2)+(c&3), pb=pa+4) so each
// GEMM's D registers land exactly in the next GEMM's B-frag element order.
// ---------------------------------------------------------------------------

#define TILE_LOAD(S, TILEEXPR)                                                 \
  const int tile##S = (TILEEXPR);                                              \
  const int s0##S = tile##S * 16;                                              \
  float ctx_s##S = sg[tile##S * kCTX + c];                                     \
  float ctx_n##S = nz[tile##S * kCTX + c];                                     \
  float ctx_m##S = mu[tile##S * kCTX + c];                                     \
  const float* tr##S = traj + (size_t)(s0##S + c) * kXU;                       \
  float4 q0_##S = *reinterpret_cast<const float4*>(tr##S + 8 * g);             \
  float4 q1_##S = *reinterpret_cast<const float4*>(tr##S + 8 * g + 4);         \
  float4 qt_##S = *reinterpret_cast<const float4*>(tr##S + 32);                \
  float4 tc4_##S = *reinterpret_cast<const float4*>(tgtc + (size_t)(s0##S + c) * kK); \
  const float* gpb##S = tgtg + (size_t)(s0##S + c) * (kK * kXU);               \
  float4 tg0_##S[4], tg1_##S[4], tg2_##S[4];                                   \
  _Pragma("unroll")                                                            \
  for (int k = 0; k < 4; ++k) {                                                \
    tg0_##S[k] = *reinterpret_cast<const float4*>(gpb##S + k * kXU + 4 * g);   \
    tg1_##S[k] = *reinterpret_cast<const float4*>(gpb##S + k * kXU + 16 + 4 * g); \
    tg2_##S[k] = *reinterpret_cast<const float4*>(gpb##S + k * kXU + 32);      \
  }

#define TILE_COMPUTE(S)                                                        \
  {                                                                            \
    float ctxv = fmaf(ctx_s##S, ctx_n##S, ctx_m##S);                           \
    if (g == 0) {                                                              \
      ctx_out[tile##S * kCTX + c] = ctxv;                                      \
      errk += 0.5f * (ctx_s##S * ctx_s##S + ctx_m##S * ctx_m##S)               \
              - logf(ctx_s##S) - 0.5f;                                         \
    }                                                                          \
    Frag x0;                                                                   \
    x0.u[0] = cvtpk(q0_##S.x, q0_##S.y); x0.u[1] = cvtpk(q0_##S.z, q0_##S.w);  \
    x0.u[2] = cvtpk(q1_##S.x, q1_##S.y); x0.u[3] = cvtpk(q1_##S.z, q1_##S.w);  \
    float qta[4] = {qt_##S.x, qt_##S.y, qt_##S.z, qt_##S.w};                   \
    float va1[8];                                                              \
    _Pragma("unroll")                                                          \
    for (int i = 0; i < 8; ++i) {                                              \
      int k = 32 + 8 * g + i;                                                  \
      int ci = k - 36; ci = ci < 0 ? 0 : (ci > 15 ? 15 : ci);                  \
      float cv = __shfl(ctxv, ci);                                             \
      va1[i] = (k < 52) ? ((k < 36) ? qta[i & 3] : cv) : 0.f;                  \
    }                                                                          \
    Frag x1;                                                                   \
    x1.u[0] = cvtpk(va1[0], va1[1]); x1.u[1] = cvtpk(va1[2], va1[3]);          \
    x1.u[2] = cvtpk(va1[4], va1[5]); x1.u[3] = cvtpk(va1[6], va1[7]);          \
    f32x4 d1a = mfma16(w1a[0].v, x0.v, zro);                                   \
    d1a = mfma16(w1a[1].v, x1.v, d1a);                                         \
    f32x4 d1b = mfma16(w1b[0].v, x0.v, zro);                                   \
    d1b = mfma16(w1b[1].v, x1.v, d1b);                                         \
    float m1a[4], m1b[4], h1lo[4], h1hi[4];                                    \
    _Pragma("unroll")                                                          \
    for (int i = 0; i < 4; ++i) {                                              \
      float za = d1a[i] + b1l[i];                                              \
      float zb = d1b[i] + b1h[i];                                              \
      m1a[i] = (za > 0.f) ? 1.f : 0.f;                                         \
      m1b[i] = (zb > 0.f) ? 1.f : 0.f;                                         \
      h1lo[i] = fmaxf(za, 0.f);                                                \
      h1hi[i] = fmaxf(zb, 0.f);                                                \
    }                                                                          \
    Frag h1f;                                                                  \
    h1f.u[0] = cvtpk(h1lo[0], h1lo[1]); h1f.u[1] = cvtpk(h1lo[2], h1lo[3]);    \
    h1f.u[2] = cvtpk(h1hi[0], h1hi[1]); h1f.u[3] = cvtpk(h1hi[2], h1hi[3]);    \
    f32x4 d2a = mfma16(w2af.v, h1f.v, zro);                                    \
    f32x4 d2b = mfma16(w2bf.v, h1f.v, zro);                                    \
    float h2lo[4], h2hi[4];                                                    \
    unsigned m2lo[4], m2hi[4];                                                 \
    _Pragma("unroll")                                                          \
    for (int i = 0; i < 4; ++i) {                                              \
      float za = d2a[i] + b2l[i];                                              \
      float zb = d2b[i] + b2h[i];                                              \
      m2lo[i] = (za > 0.f) ? 0x3F80u : 0u;                                     \
      m2hi[i] = (zb > 0.f) ? 0x3F80u : 0u;                                     \
      h2lo[i] = fmaxf(za, 0.f);                                                \
      h2hi[i] = fmaxf(zb, 0.f);                                                \
    }                                                                          \
    Frag h2f;                                                                  \
    h2f.u[0] = cvtpk(h2lo[0], h2lo[1]); h2f.u[1] = cvtpk(h2lo[2], h2lo[3]);    \
    h2f.u[2] = cvtpk(h2hi[0], h2hi[1]); h2f.u[3] = cvtpk(h2hi[2], h2hi[3]);    \
    Frag m2f;                                                                  \
    m2f.u[0] = m2lo[0] | (m2lo[1] << 16); m2f.u[1] = m2lo[2] | (m2lo[3] << 16);\
    m2f.u[2] = m2hi[0] | (m2hi[1] << 16); m2f.u[3] = m2hi[2] | (m2hi[3] << 16);\
    f32x4 pacc = mfma16(w3f.v, h2f.v, zro);                                    \
    if (g == 0) {                                                              \
      float tv[4] = {tc4_##S.x, tc4_##S.y, tc4_##S.z, tc4_##S.w};              \
      _Pragma("unroll")                                                        \
      for (int i = 0; i < 4; ++i) {                                            \
        float d = (pacc[i] + b3a[i]) - tv[i];                                  \
        errc = fmaf(d, d, errc);                                               \
      }                                                                        \
    }                                                                          \
    _Pragma("unroll")                                                          \
    for (int k = 0; k < 4; ++k) {                                              \
      f32x4 ca = mfma16(uka[k].v, m2f.v, zro);                                 \
      f32x4 cb = mfma16(ukb[k].v, m2f.v, zro);                                 \
      float ta[4], tb[4];                                                      \
      _Pragma("unroll")                                                        \
      for (int i = 0; i < 4; ++i) {                                            \
        ta[i] = ca[i] * m1a[i];                                                \
        tb[i] = cb[i] * m1b[i];                                                \
      }                                                                        \
      Frag tf;                                                                 \
      tf.u[0] = cvtpk(ta[0], ta[1]); tf.u[1] = cvtpk(ta[2], ta[3]);            \
      tf.u[2] = cvtpk(tb[0], tb[1]); tf.u[3] = cvtpk(tb[2], tb[3]);            \
      _Pragma("unroll")                                                        \
      for (int jj = 0; jj < 3; ++jj) {                                         \
        f32x4 j4 = mfma16(w1vf[jj].v, tf.v, zro);                              \
        if (jj == 0) {                                                         \
          float tv[4] = {tg0_##S[k].x, tg0_##S[k].y, tg0_##S[k].z, tg0_##S[k].w}; \
          _Pragma("unroll")                                                    \
          for (int i = 0; i < 4; ++i) {                                        \
            float d = j4[i] - tv[i];                                           \
            errg = fmaf(d, d, errg);                                           \
          }                                                                    \
        } else if (jj == 1) {                                                  \
          float tv[4] = {tg1_##S[k].x, tg1_##S[k].y, tg1_##S[k].z, tg1_##S[k].w}; \
          _Pragma("unroll")                                                    \
          for (int i = 0; i < 4; ++i) {                                        \
            float d = j4[i] - tv[i];                                           \
            errg = fmaf(d, d, errg);                                           \
          }                                                                    \
        } else if (g == 0) {                                                   \
          float tv[4] = {tg2_##S[k].x, tg2_##S[k].y, tg2_##S[k].z, tg2_##S[k].w}; \
          _Pragma("unroll")                                                    \
          for (int i = 0; i < 4; ++i) {                                        \
            float d = j4[i] - tv[i];                                           \
            errg = fmaf(d, d, errg);                                           \
          }                                                                    \
        }                                                                      \
      }                                                                        \
    }                                                                          \
  }

__global__ __launch_bounds__(256, 2) void main_mfma(
    const float* __restrict__ traj, const float* __restrict__ tgtc,
    const float* __restrict__ tgtg, const float* __restrict__ mu,
    const float* __restrict__ sg, const float* __restrict__ nz,
    const float* __restrict__ W1, const float* __restrict__ b1,
    const float* __restrict__ W2, const float* __restrict__ b2,
    const float* __restrict__ W3, const float* __restrict__ b3,
    float* __restrict__ ctx_out,
    float* __restrict__ pc, float* __restrict__ pg, float* __restrict__ pk)
{
  const int tid = threadIdx.x;
  const int l = tid & 63;
  const int g = l >> 4;       // k-chunk group
  const int c = l & 15;       // sample column / A-row
  const int wid = blockIdx.x * 4 + (tid >> 6);
  const int pa = 8 * (c >> 2) + (c & 3);   // permuted feature for A rows (1st half)
  const int pb = pa + 4;                   // 2nd half

  const f32x4 zro = {0.f, 0.f, 0.f, 0.f};

  // ===================== prologue: weight fragments =====================
  Frag w1a[2], w1b[2];
#pragma unroll
  for (int kt = 0; kt < 2; ++kt) {
    float va[8], vb[8];
#pragma unroll
    for (int i = 0; i < 8; ++i) {
      int kk = kt * 32 + 8 * g + i;
      va[i] = (kk < 52) ? W1[kk * 32 + pa] : 0.f;
      vb[i] = (kk < 52) ? W1[kk * 32 + pb] : 0.f;
    }
#pragma unroll
    for (int q = 0; q < 4; ++q) {
      w1a[kt].u[q] = cvtpk(va[2 * q], va[2 * q + 1]);
      w1b[kt].u[q] = cvtpk(vb[2 * q], vb[2 * q + 1]);
    }
  }

  Frag w2af, w2bf;
  {
    float va[8], vb[8];
#pragma unroll
    for (int i = 0; i < 8; ++i) {
      va[i] = W2[(8 * g + i) * 32 + pa];
      vb[i] = W2[(8 * g + i) * 32 + pb];
    }
#pragma unroll
    for (int q = 0; q < 4; ++q) {
      w2af.u[q] = cvtpk(va[2 * q], va[2 * q + 1]);
      w2bf.u[q] = cvtpk(vb[2 * q], vb[2 * q + 1]);
    }
  }

  Frag w3f;
  {
    float va[8];
#pragma unroll
    for (int i = 0; i < 8; ++i)
      va[i] = (c < 4) ? W3[(8 * g + i) * 4 + c] : 0.f;
#pragma unroll
    for (int q = 0; q < 4; ++q) w3f.u[q] = cvtpk(va[2 * q], va[2 * q + 1]);
  }

  // U_k^T A-frags: U_k^T[j][h] = W3[h][k]*W2[j][h], rows j permuted.
  float w3v[8][4];
#pragma unroll
  for (int i = 0; i < 8; ++i) {
    float4 q = *reinterpret_cast<const float4*>(W3 + (8 * g + i) * 4);
    w3v[i][0] = q.x; w3v[i][1] = q.y; w3v[i][2] = q.z; w3v[i][3] = q.w;
  }
  float w2ra[8], w2rb[8];
  {
    float4 a0 = *reinterpret_cast<const float4*>(W2 + pa * 32 + 8 * g);
    float4 a1 = *reinterpret_cast<const float4*>(W2 + pa * 32 + 8 * g + 4);
    float4 b0 = *reinterpret_cast<const float4*>(W2 + pb * 32 + 8 * g);
    float4 b1q = *reinterpret_cast<const float4*>(W2 + pb * 32 + 8 * g + 4);
    w2ra[0]=a0.x; w2ra[1]=a0.y; w2ra[2]=a0.z; w2ra[3]=a0.w;
    w2ra[4]=a1.x; w2ra[5]=a1.y; w2ra[6]=a1.z; w2ra[7]=a1.w;
    w2rb[0]=b0.x; w2rb[1]=b0.y; w2rb[2]=b0.z; w2rb[3]=b0.w;
    w2rb[4]=b1q.x; w2rb[5]=b1q.y; w2rb[6]=b1q.z; w2rb[7]=b1q.w;
  }
  Frag uka[4], ukb[4];
#pragma unroll
  for (int k = 0; k < 4; ++k) {
#pragma unroll
    for (int q = 0; q < 4; ++q) {
      uka[k].u[q] = cvtpk(w3v[2*q][k] * w2ra[2*q], w3v[2*q+1][k] * w2ra[2*q+1]);
      ukb[k].u[q] = cvtpk(w3v[2*q][k] * w2rb[2*q], w3v[2*q+1][k] * w2rb[2*q+1]);
    }
  }

  // J A-frags: rows x natural (output stays in D layout for float4 target cmp)
  Frag w1vf[3];
#pragma unroll
  for (int jj = 0; jj < 3; ++jj) {
    int x = 16 * jj + c;
    float va[8] = {0,0,0,0,0,0,0,0};
    if (x < kXU) {
      float4 p0 = *reinterpret_cast<const float4*>(W1 + x * 32 + 8 * g);
      float4 p1 = *reinterpret_cast<const float4*>(W1 + x * 32 + 8 * g + 4);
      va[0]=p0.x; va[1]=p0.y; va[2]=p0.z; va[3]=p0.w;
      va[4]=p1.x; va[5]=p1.y; va[6]=p1.z; va[7]=p1.w;
    }
#pragma unroll
    for (int q = 0; q < 4; ++q) w1vf[jj].u[q] = cvtpk(va[2*q], va[2*q+1]);
  }

  // biases (per-lane feature sets)
  float b1l[4], b1h[4], b2l[4], b2h[4], b3a[4];
  {
    float4 t0 = *reinterpret_cast<const float4*>(b1 + 8 * g);
    float4 t1 = *reinterpret_cast<const float4*>(b1 + 8 * g + 4);
    b1l[0]=t0.x; b1l[1]=t0.y; b1l[2]=t0.z; b1l[3]=t0.w;
    b1h[0]=t1.x; b1h[1]=t1.y; b1h[2]=t1.z; b1h[3]=t1.w;
    float4 r0 = *reinterpret_cast<const float4*>(b2 + 8 * g);
    float4 r1 = *reinterpret_cast<const float4*>(b2 + 8 * g + 4);
    b2l[0]=r0.x; b2l[1]=r0.y; b2l[2]=r0.z; b2l[3]=r0.w;
    b2h[0]=r1.x; b2h[1]=r1.y; b2h[2]=r1.z; b2h[3]=r1.w;
    float4 s0q = *reinterpret_cast<const float4*>(b3);
    b3a[0]=s0q.x; b3a[1]=s0q.y; b3a[2]=s0q.z; b3a[3]=s0q.w;
  }

  // ===================== 4-tile software pipeline =====================
  float errc = 0.f, errg = 0.f, errk = 0.f;

  TILE_LOAD(A, wid * 4)
  TILE_LOAD(B, wid * 4 + 1)
  __builtin_amdgcn_sched_barrier(0);
  TILE_COMPUTE(A)
  TILE_LOAD(C, wid * 4 + 2)
  __builtin_amdgcn_sched_barrier(0);
  TILE_COMPUTE(B)
  TILE_LOAD(D, wid * 4 + 3)
  __builtin_amdgcn_sched_barrier(0);
  TILE_COMPUTE(C)
  TILE_COMPUTE(D)

  // ---- wave reduction (deterministic), one partial triple per wave ----
#pragma unroll
  for (int off = 32; off > 0; off >>= 1) {
    errc += __shfl_down(errc, off);
    errg += __shfl_down(errg, off);
    errk += __shfl_down(errk, off);
  }
  if (l == 0) { pc[wid] = errc; pg[wid] = errg; pk[wid] = errk; }
}

// ---------------------------------------------------------------------------
// finalize: reduce 2048 pc + 2048 pg + 2048 pk partials, write loss
// ---------------------------------------------------------------------------
__global__ __launch_bounds__(256) void finalize_kernel(
    const float* __restrict__ ws, float* __restrict__ out)
{
  const int tid = threadIdx.x;
  float cs = 0.f, gs = 0.f, ks = 0.f;
#pragma unroll
  for (int i = 0; i < 8; ++i) {
    cs += ws[tid + i * 256];
    gs += ws[kNW + tid + i * 256];
    ks += ws[2 * kNW + tid + i * 256];
  }
  __shared__ float rc[256], rg[256], rk[256];
  rc[tid] = cs; rg[tid] = gs; rk[tid] = ks;
  __syncthreads();
  for (int off = 128; off > 0; off >>= 1) {
    if (tid < off) {
      rc[tid] += rc[tid + off];
      rg[tid] += rg[tid + off];
      rk[tid] += rk[tid + off];
    }
    __syncthreads();
  }
  if (tid == 0) {
    out[0] = rc[0] / (float)(kBT * kK)
           + rg[0] / ((float)kBT * (float)(kK * kXU))
           + rk[0] / (float)(kB * kCTX);
  }
}

// ---------------------------------------------------------------------------
extern "C" void kernel_launch(void* const* d_in, const int* in_sizes, int n_in,
                              void* d_out, int out_size, void* d_ws, size_t ws_size,
                              hipStream_t stream)
{
  const float* traj = (const float*)d_in[0];
  const float* tgtc = (const float*)d_in[1];
  const float* tgtg = (const float*)d_in[2];
  const float* mu   = (const float*)d_in[3];
  const float* sg   = (const float*)d_in[4];
  const float* nz   = (const float*)d_in[5];
  const float* W1   = (const float*)d_in[6];
  const float* b1   = (const float*)d_in[7];
  const float* W2   = (const float*)d_in[8];
  const float* b2   = (const float*)d_in[9];
  const float* W3   = (const float*)d_in[10];
  const float* b3   = (const float*)d_in[11];

  float* out = (float*)d_out;
  float* ws  = (float*)d_ws;
  float* pc  = ws;                 // [0, 2048)
  float* pg  = ws + kNW;           // [2048, 4096)
  float* pk  = ws + 2 * kNW;       // [4096, 6144)

  main_mfma<<<kMainBlocks, 256, 0, stream>>>(traj, tgtc, tgtg, mu, sg, nz,
                                             W1, b1, W2, b2, W3, b3,
                                             out + 1, pc, pg, pk);
  finalize_kernel<<<1, 256, 0, stream>>>(ws, out);
}